// Round 9
// baseline (276.815 us; speedup 1.0000x reference)
//
#include <hip/hip_runtime.h>
#include <hip/hip_bf16.h>

#define NNODES 50000
#define NPAD   50048                 // 3128 row-tiles of 16 (covers 391*128)
#define NEDGES 800000
#define CAP 64                       // padded-CSR capacity (max degree ~45, Poisson(16))
#define RSQRT_D 0.17677669529663687f // 1/sqrt(32)
#define INV65535 1.5259021896696422e-05f

#define GEMM_BLOCKS 1564             // 391 stripes x 4 ct-groups
#define EHALF 400384                 // GEMM_BLOCKS*256 (edge e and e+EHALF per thread)

#define PACKA_BLOCKS 6256            // NPAD*32/256
#define PREPW_BLOCKS 416
#define CNT_BLOCKS   196             // ceil(NNODES/256)

typedef short short8 __attribute__((ext_vector_type(8)));   // 8 bf16 (4 VGPRs)
typedef float f32x4 __attribute__((ext_vector_type(4)));    // MFMA accumulator
typedef unsigned uint2v __attribute__((ext_vector_type(2)));
typedef unsigned uint4v __attribute__((ext_vector_type(4)));
typedef float float4v __attribute__((ext_vector_type(4)));

__device__ inline unsigned short f2bf(float f) {
    union { float f; unsigned u; } v; v.f = f;
    unsigned r = (v.u + 0x7fff + ((v.u >> 16) & 1)) >> 16;   // round-to-nearest-even
    return (unsigned short)r;
}
__device__ inline float bf2f(unsigned short u) {
    union { unsigned u; float f; } v; v.u = ((unsigned)u) << 16;
    return v.f;
}
// packed-bf16 dword -> two floats: 1 VALU op each (lshl / and)
__device__ inline float bflo(unsigned u) {
    union { unsigned u; float f; } v; v.u = u << 16; return v.f;
}
__device__ inline float bfhi(unsigned u) {
    union { unsigned u; float f; } v; v.u = u & 0xffff0000u; return v.f;
}
// branch-free tanh: 1 - 2/(e^{2x}+1). ~1e-6 abs err, saturates correctly.
__device__ inline float fast_tanh(float v) {
    const float e = __expf(2.0f * v);
    return 1.0f - 2.0f * __builtin_amdgcn_rcpf(e + 1.0f);
}

// ---------------------------------------------------------------------------
// prep_pack: FUSED prep_w + pack_a + cnt-zero.
// Block-range split: [0,6256) pack_a, [6256,6672) prep_w, [6672,6868) cnt.
// ---------------------------------------------------------------------------
__global__ __launch_bounds__(256) void prep_pack(
    const float* __restrict__ Wq, const float* __restrict__ bq,
    const float* __restrict__ Wk, const float* __restrict__ bk,
    const float* __restrict__ Wv, const float* __restrict__ bv,
    const float* __restrict__ Wskip, const float* __restrict__ bskip,
    const float* __restrict__ x, const float* __restrict__ t,
    unsigned short* __restrict__ Wtf, float* __restrict__ biascat,
    unsigned short* __restrict__ y0f, int* __restrict__ cnt)
{
    const int b = blockIdx.x;
    const int tid = threadIdx.x;

    if (b < PACKA_BLOCKS) {
        // ---- pack_a: y0 = [x, x*t] -> bf16 frag-major y0f ----
        const int gid = b * 256 + tid;                 // NPAD*32 threads exactly
        const int row = gid >> 5;
        const int oct = gid & 31;                      // kt*4+quad
        short8 out = {0, 0, 0, 0, 0, 0, 0, 0};
        if (row < NNODES) {
            const int kb = oct * 8;
            const int kx = (kb < 128) ? kb : (kb - 128);
            const float* xr = x + (size_t)row * 128 + kx;
            float4 f0 = *(const float4*)xr;
            float4 f1 = *(const float4*)(xr + 4);
            if (kb >= 128) {
                const float tv = t[row];
                f0.x *= tv; f0.y *= tv; f0.z *= tv; f0.w *= tv;
                f1.x *= tv; f1.y *= tv; f1.z *= tv; f1.w *= tv;
            }
            out[0] = (short)f2bf(f0.x); out[1] = (short)f2bf(f0.y);
            out[2] = (short)f2bf(f0.z); out[3] = (short)f2bf(f0.w);
            out[4] = (short)f2bf(f1.x); out[5] = (short)f2bf(f1.y);
            out[6] = (short)f2bf(f1.z); out[7] = (short)f2bf(f1.w);
        }
        *(short8*)(y0f + (size_t)((row >> 4) * 32 + oct) * 128 + (row & 15) * 8) = out;
        return;
    }
    const int b2 = b - PACKA_BLOCKS;
    if (b2 < PREPW_BLOCKS) {
        // ---- prep_w: Wtf frag-major; chunk (ct*32+kt*4+quad) = 16 cols x 8 k ----
        const int col = b2;
        const int k = tid;
        float v; float bb;
        if (col < 128)      { v = Wq[k * 128 + col];          bb = bq[col]; }
        else if (col < 256) { v = Wk[k * 128 + col - 128];    bb = bk[col - 128]; }
        else if (col < 384) { v = Wv[k * 128 + col - 256];    bb = bv[col - 256]; }
        else                { v = Wskip[k * 32 + col - 384];  bb = bskip[col - 384]; }
        const int ct = col >> 4, c16 = col & 15;
        const int kt = k >> 5, quad = (k >> 3) & 3, j = k & 7;
        Wtf[(size_t)(ct * 32 + kt * 4 + quad) * 128 + c16 * 8 + j] = f2bf(v);
        if (k == 0) biascat[col] = bb;
        return;
    }
    // ---- cnt zero ----
    const int idx = (b2 - PREPW_BLOCKS) * 256 + tid;
    if (idx < NNODES) cnt[idx] = 0;
}

// ---------------------------------------------------------------------------
// gemm_scatter v5: v4 + NON-TEMPORAL stores. Round-8 falsified the payload
// theory (4B entries: WRITE unchanged at ~102MB, time unchanged at 70us).
// Mechanism: einfo lines ping-pong across the 8 non-coherent XCD L2s —
// each of 800K random stores RFO-fetches a 64B line into its XCD, dirties
// 4B, next store from another XCD steals it: ~51MB fetch + 51MB writeback
// regardless of entry size. Fix: `nt` stores (no L2 allocate, posted
// sector write) for einfo AND for the streaming Qb/KVb/S outputs (never
// re-read in-kernel) — kills the ping-pong, frees L2 for y0f reuse.
// gemm structure unchanged: by-split, 1564 short blocks, zero-LDS.
// ---------------------------------------------------------------------------
#define LOADW(buf, ct) do {                                                    \
    _Pragma("unroll")                                                          \
    for (int kt_ = 0; kt_ < 8; ++kt_)                                          \
        buf[kt_] = *(const short8*)(Wtf + (size_t)((ct) * 32 + kt_ * 4 + quad) * 128 + l16 * 8); \
} while (0)

#define DOTILE(buf, ct) do {                                                   \
    f32x4 acc0 = {0.f, 0.f, 0.f, 0.f}, acc1 = {0.f, 0.f, 0.f, 0.f};            \
    _Pragma("unroll")                                                          \
    for (int kt_ = 0; kt_ < 8; ++kt_) {                                        \
        acc0 = __builtin_amdgcn_mfma_f32_16x16x32_bf16(buf[kt_], b0[kt_], acc0, 0, 0, 0); \
        acc1 = __builtin_amdgcn_mfma_f32_16x16x32_bf16(buf[kt_], b1[kt_], acc1, 0, 0, 0); \
    }                                                                          \
    const int cb_ = (ct) * 16 + quad * 4;                                      \
    const float4 bias_ = *(const float4*)(biascat + cb_);                      \
    _Pragma("unroll")                                                          \
    for (int s_ = 0; s_ < 2; ++s_) {                                           \
        const int m_ = n0 + s_ * 16 + l16;                                     \
        if (m_ < NNODES) {                                                     \
            const f32x4 a_ = s_ ? acc1 : acc0;                                 \
            const float v0_ = a_[0] + bias_.x, v1_ = a_[1] + bias_.y;          \
            const float v2_ = a_[2] + bias_.z, v3_ = a_[3] + bias_.w;          \
            if ((ct) < 24) {                                                   \
                uint2v pk_;                                                    \
                pk_.x = (unsigned)f2bf(v0_) | ((unsigned)f2bf(v1_) << 16);     \
                pk_.y = (unsigned)f2bf(v2_) | ((unsigned)f2bf(v3_) << 16);     \
                if ((ct) < 8)                                                  \
                    __builtin_nontemporal_store(pk_,                           \
                        (uint2v*)(Qb + (size_t)m_ * 128 + cb_));               \
                else                                                           \
                    __builtin_nontemporal_store(pk_,                           \
                        (uint2v*)(KVb + (size_t)m_ * 256 + (cb_ - 128)));      \
            } else {                                                           \
                float4v sv_; sv_.x = v0_; sv_.y = v1_; sv_.z = v2_; sv_.w = v3_; \
                __builtin_nontemporal_store(sv_,                               \
                    (float4v*)(S + (size_t)m_ * 32 + (cb_ - 384)));            \
            }                                                                  \
        }                                                                      \
    }                                                                          \
} while (0)

__global__ __launch_bounds__(256) void gemm_scatter(
    const unsigned short* __restrict__ y0f,
    const unsigned short* __restrict__ Wtf,
    const float* __restrict__ biascat,
    unsigned short* __restrict__ Qb, unsigned short* __restrict__ KVb,
    float* __restrict__ S,
    const int* __restrict__ ei, const float* __restrict__ ew,
    int* __restrict__ cnt, unsigned* __restrict__ einfo)
{
    const int g = blockIdx.x;                          // 0..1563
    const int tid = threadIdx.x;

    // ---- scatter prologue: issue coalesced edge loads first ----
    const int gid = g * 256 + tid;                     // 0..400383
    const int e0 = gid;
    const int e1 = gid + EHALF;
    const bool m1 = e1 < NEDGES;                       // block-uniform (g>=1561 false)
    const int  s0 = ei[e0];
    const int  d0 = ei[NEDGES + e0];
    const float w0 = ew[e0];
    int s1 = 0, d1 = 0; float w1 = 0.f;
    if (m1) { s1 = ei[e1]; d1 = ei[NEDGES + e1]; w1 = ew[e1]; }

    // ---- gemm setup ----
    const int bx = g % 391;
    const int by = g / 391;                            // 0..3
    const int wave = tid >> 6;
    const int lane = tid & 63;
    const int l16 = lane & 15;
    const int quad = lane >> 4;

    const int n0 = bx * 128 + wave * 32;               // 32 rows per wave
    const int mt0 = n0 >> 4;
    const int ct0 = by * 7 - ((by >= 2) ? (by - 2) : 0);   // 0,7,14,20
    const int nct = (by < 2) ? 7 : 6;
    const int ctEnd = ct0 + nct;

    // y0 B-frags for both 16-row sets: 1024B coalesced per load
    short8 b0[8], b1[8];
    #pragma unroll
    for (int kt = 0; kt < 8; ++kt) {
        b0[kt] = *(const short8*)(y0f + (size_t)((mt0 + 0) * 32 + kt * 4 + quad) * 128 + l16 * 8);
        b1[kt] = *(const short8*)(y0f + (size_t)((mt0 + 1) * 32 + kt * 4 + quad) * 128 + l16 * 8);
    }

    // ---- fire atomics (round trip hides under the first tiles) ----
    const int pos0 = atomicAdd(&cnt[d0], 1);
    const int pos1 = m1 ? atomicAdd(&cnt[d1], 1) : CAP;

    short8 wa[8], wb[8];                               // ping-pong Wt A-frags
    LOADW(wa, ct0);
    LOADW(wb, ct0 + 1);
    DOTILE(wa, ct0);

    // ---- scatter epilogue: 4B packed entries, NON-TEMPORAL ----
    if (pos0 < CAP) {
        const unsigned wq = (unsigned)(w0 * 65535.f + 0.5f);
        __builtin_nontemporal_store(((unsigned)s0 << 16) | wq,
                                    einfo + (size_t)d0 * CAP + pos0);
    }
    if (pos1 < CAP) {
        const unsigned wq = (unsigned)(w1 * 65535.f + 0.5f);
        __builtin_nontemporal_store(((unsigned)s1 << 16) | wq,
                                    einfo + (size_t)d1 * CAP + pos1);
    }

    for (int ct = ct0 + 1; ct < ctEnd; ct += 2) {
        if (ct + 1 < ctEnd) LOADW(wa, ct + 1);
        DOTILE(wb, ct);
        if (ct + 1 < ctEnd) {
            if (ct + 2 < ctEnd) LOADW(wb, ct + 2);
            DOTILE(wa, ct + 1);
        }
    }
}

// ---------------------------------------------------------------------------
// agg_pass (v2 structure + 4B einfo + nt read-once loads): one wave per
// node; 16 lanes per edge (4 edges per batch), 16B (8 bf16 dims) per lane;
// 1-batch-ahead pipeline. einfo row + Qb row are read-ONCE -> nontemporal
// loads (don't evict KVb gather lines, which have ~16x reuse).
// Decode: src = e>>16 (<<9 = *512B row), w = (e&0xffff)/65535.
// Rank-1 edge-attr decomposition: p*(v+e) = p*v + (p*w)*We + p*be.
// ---------------------------------------------------------------------------
__global__ __launch_bounds__(256) void agg_pass(
    const int* __restrict__ cnt, const unsigned* __restrict__ einfo,
    const float* __restrict__ We, const float* __restrict__ be,
    const unsigned short* __restrict__ Qb, const unsigned short* __restrict__ KVb,
    float* __restrict__ G)
{
    const int tid = threadIdx.x;
    const int node = blockIdx.x * 4 + (tid >> 6);
    if (node >= NNODES) return;
    const int l = tid & 63;
    const int slot = l >> 4;      // which edge of the 4-batch
    const int q = l & 15;         // 16 lanes/edge; lane covers dims q*8..q*8+7

    // Q fragment: 8 bf16 -> 8 f32 (read-once: nt load)
    const uint4v qu = __builtin_nontemporal_load(
        (const uint4v*)(Qb + (size_t)node * 128 + q * 8));
    float qv[8];
    qv[0] = bflo(qu.x); qv[1] = bfhi(qu.x);
    qv[2] = bflo(qu.y); qv[3] = bfhi(qu.y);
    qv[4] = bflo(qu.z); qv[5] = bfhi(qu.z);
    qv[6] = bflo(qu.w); qv[7] = bfhi(qu.w);

    // We/be fragments for this lane's 8 dims (tiny, L2-hot)
    const float4 weA = *(const float4*)(We + q * 8);
    const float4 weB = *(const float4*)(We + q * 8 + 4);
    const float4 beA = *(const float4*)(be + q * 8);
    const float4 beB = *(const float4*)(be + q * 8 + 4);

    // per-head q.We / q.be scalars: partial over 8 dims, reduce over the
    // 4-lane head group (xor 1,2)
    float pw = qv[0]*weA.x + qv[1]*weA.y + qv[2]*weA.z + qv[3]*weA.w
             + qv[4]*weB.x + qv[5]*weB.y + qv[6]*weB.z + qv[7]*weB.w;
    float pb = qv[0]*beA.x + qv[1]*beA.y + qv[2]*beA.z + qv[3]*beA.w
             + qv[4]*beB.x + qv[5]*beB.y + qv[6]*beB.z + qv[7]*beB.w;
    pw += __shfl_xor(pw, 1); pb += __shfl_xor(pb, 1);
    pw += __shfl_xor(pw, 2); pb += __shfl_xor(pb, 2);
    const float qWeS = pw * RSQRT_D;
    const float qbeS = pb * RSQRT_D;

    const int deg = min(cnt[node], CAP);
    const unsigned* ep = einfo + (size_t)node * CAP;

    // whole CSR row in wave registers (one 256B coalesced nt load); zeros
    // elsewhere so shuffled-in garbage is a safe node-0 index / weight-0
    unsigned eall = 0;
    const int loadN = min(CAP, ((deg + 3) & ~3) + 4);
    if (l < loadN) eall = __builtin_nontemporal_load(ep + l);

    float a[8] = {0.f, 0.f, 0.f, 0.f, 0.f, 0.f, 0.f, 0.f};
    float sp = 0.f, spw = 0.f;

    const char* kvb = (const char*)KVb;          // KV row = 512B (K:0..255, V:256..511)
    const unsigned qoff = (unsigned)(q * 16);

    // prologue: fetch batch 0
    unsigned ec = (unsigned)__shfl((int)eall, slot);
    bool vc = (slot < deg);
    {
        const unsigned off = (vc ? ((ec & 0xffff0000u) >> 7) : 0u) + qoff;
        uint4 kw = *(const uint4*)(kvb + off);
        uint4 vw = *(const uint4*)(kvb + off + 256);
        float wc = (float)(ec & 0xffffu) * INV65535;

        for (int jj = 0; jj < deg; jj += 4) {
            // --- prefetch next batch (issued before current compute) ---
            const int nidx = (jj + 4 + slot) & 63;
            const unsigned en = (unsigned)__shfl((int)eall, nidx);
            const bool vn = (jj + 4 + slot < deg);
            const unsigned offn = (vn ? ((en & 0xffff0000u) >> 7) : 0u) + qoff;
            const uint4 kwn = *(const uint4*)(kvb + offn);
            const uint4 vwn = *(const uint4*)(kvb + offn + 256);
            const float wn = (float)(en & 0xffffu) * INV65535;

            // --- compute current batch ---
            float d = qv[0]*bflo(kw.x) + qv[1]*bfhi(kw.x)
                    + qv[2]*bflo(kw.y) + qv[3]*bfhi(kw.y)
                    + qv[4]*bflo(kw.z) + qv[5]*bfhi(kw.z)
                    + qv[6]*bflo(kw.w) + qv[7]*bfhi(kw.w);
            d += __shfl_xor(d, 1);
            d += __shfl_xor(d, 2);               // full per-head dot on all 4 lanes
            float p = __expf(d * RSQRT_D + wc * qWeS + qbeS);
            p = vc ? p : 0.f;
            sp += p; spw += p * wc;
            a[0] += p * bflo(vw.x); a[1] += p * bfhi(vw.x);
            a[2] += p * bflo(vw.y); a[3] += p * bfhi(vw.y);
            a[4] += p * bflo(vw.z); a[5] += p * bfhi(vw.z);
            a[6] += p * bflo(vw.w); a[7] += p * bfhi(vw.w);

            kw = kwn; vw = vwn; wc = wn; vc = vn;
        }
    }

    // reduce over the 4 edge slots (lane bits 4,5)
    sp  += __shfl_xor(sp, 16);  sp  += __shfl_xor(sp, 32);
    spw += __shfl_xor(spw, 16); spw += __shfl_xor(spw, 32);
    #pragma unroll
    for (int i = 0; i < 8; ++i) {
        a[i] += __shfl_xor(a[i], 16);
        a[i] += __shfl_xor(a[i], 32);
    }

    // per-head normalize + rank-1 edge-attr contribution
    const float inv = 1.f / (sp + 1e-16f);
    a[0] = (a[0] + spw*weA.x + sp*beA.x) * inv;
    a[1] = (a[1] + spw*weA.y + sp*beA.y) * inv;
    a[2] = (a[2] + spw*weA.z + sp*beA.z) * inv;
    a[3] = (a[3] + spw*weA.w + sp*beA.w) * inv;
    a[4] = (a[4] + spw*weB.x + sp*beB.x) * inv;
    a[5] = (a[5] + spw*weB.y + sp*beB.y) * inv;
    a[6] = (a[6] + spw*weB.z + sp*beB.z) * inv;
    a[7] = (a[7] + spw*weB.w + sp*beB.w) * inv;

    // mean over the 4 heads (lane bits 2,3)
    #pragma unroll
    for (int i = 0; i < 8; ++i) {
        a[i] += __shfl_xor(a[i], 4);
        a[i] += __shfl_xor(a[i], 8);
    }

    if (l < 4) {   // slot 0, q = 0..3 -> dims q*8..q*8+7
        *(float4*)(G + (size_t)node * 32 + q * 8) =
            make_float4(a[0]*0.25f, a[1]*0.25f, a[2]*0.25f, a[3]*0.25f);
        *(float4*)(G + (size_t)node * 32 + q * 8 + 4) =
            make_float4(a[4]*0.25f, a[5]*0.25f, a[6]*0.25f, a[7]*0.25f);
    }
}

// ---------------------------------------------------------------------------
// node_pass (v2): Wm lives in VGPRs, not LDS. Each thread's column pair
// (c, c+128) with c = tid&127 is invariant across the node loop; the 64
// weights fit in 64 VGPRs, loaded ONCE from global (coalesced, L2-hot).
// LDS keeps only yl (8 KB). Inner loop per node: 8 broadcast ds_read_b128
// + 64 reg-reg FMAs + 2 fast_tanh.
// ---------------------------------------------------------------------------
__global__ __launch_bounds__(256, 4) void node_pass(
    const float* __restrict__ x,
    const float* __restrict__ G, const float* __restrict__ S,
    const float* __restrict__ Wmlp, const float* __restrict__ bmlp,
    float* __restrict__ out)
{
    __shared__ float yl[64 * 32];

    const int tid = threadIdx.x;
    const int c = tid & 127;            // fixed output column pair (c, c+128)
    const int half = tid >> 7;          // which node of each row pair

    float w1[32], w2[32];
    #pragma unroll
    for (int d = 0; d < 32; ++d) {
        w1[d] = Wmlp[d * 256 + c];
        w2[d] = Wmlp[d * 256 + c + 128];
    }
    const float b1 = bmlp[c];
    const float b2 = bmlp[c + 128];

    const int n0 = blockIdx.x * 64;

    // stage y = tanh(G+S): 512 float4s by 256 threads, vectorized
    for (int i4 = tid; i4 < 512; i4 += 256) {
        const int n = n0 + (i4 >> 3);
        const int d0 = (i4 & 7) * 4;
        float4 yv = make_float4(0.f, 0.f, 0.f, 0.f);
        if (n < NNODES) {
            const float4 gv = *(const float4*)(G + (size_t)n * 32 + d0);
            const float4 sv = *(const float4*)(S + (size_t)n * 32 + d0);
            yv.x = fast_tanh(gv.x + sv.x);
            yv.y = fast_tanh(gv.y + sv.y);
            yv.z = fast_tanh(gv.z + sv.z);
            yv.w = fast_tanh(gv.w + sv.w);
        }
        *(float4*)&yl[i4 * 4] = yv;
    }
    __syncthreads();

    for (int k = 0; k < 32; ++k) {
        const int nl = 2 * k + half;
        const int n = n0 + nl;
        if (n >= NNODES) continue;

        const float4* yr = (const float4*)&yl[nl * 32];  // wave-uniform -> broadcast
        float s1 = b1, s2 = b2;
        #pragma unroll
        for (int d8 = 0; d8 < 8; ++d8) {
            const float4 y4 = yr[d8];
            s1 = fmaf(y4.x, w1[d8 * 4 + 0], s1);
            s2 = fmaf(y4.x, w2[d8 * 4 + 0], s2);
            s1 = fmaf(y4.y, w1[d8 * 4 + 1], s1);
            s2 = fmaf(y4.y, w2[d8 * 4 + 1], s2);
            s1 = fmaf(y4.z, w1[d8 * 4 + 2], s1);
            s2 = fmaf(y4.z, w2[d8 * 4 + 2], s2);
            s1 = fmaf(y4.w, w1[d8 * 4 + 3], s1);
            s2 = fmaf(y4.w, w2[d8 * 4 + 3], s2);
        }
        const float z1 = fast_tanh(s1);
        const float z2 = fast_tanh(s2);
        out[(size_t)n * 128 + c] = fmaf(x[(size_t)n * 128 + c], z1, z2);
    }
}

// ---------------------------------------------------------------------------
extern "C" void kernel_launch(void* const* d_in, const int* in_sizes, int n_in,
                              void* d_out, int out_size, void* d_ws, size_t ws_size,
                              hipStream_t stream) {
    const float* x     = (const float*)d_in[0];
    const float* t     = (const float*)d_in[1];
    const int*   ei    = (const int*)  d_in[2];
    const float* ew    = (const float*)d_in[3];
    const float* Wq    = (const float*)d_in[4];
    const float* bq    = (const float*)d_in[5];
    const float* Wk    = (const float*)d_in[6];
    const float* bk    = (const float*)d_in[7];
    const float* Wv    = (const float*)d_in[8];
    const float* bv    = (const float*)d_in[9];
    const float* We    = (const float*)d_in[10];
    const float* be    = (const float*)d_in[11];
    const float* Wskip = (const float*)d_in[12];
    const float* bskip = (const float*)d_in[13];
    const float* Wmlp  = (const float*)d_in[14];
    const float* bmlp  = (const float*)d_in[15];

    char* p = (char*)d_ws;
    unsigned short* Qb  = (unsigned short*)p; p += (size_t)NNODES * 128 * 2;
    unsigned short* KVb = (unsigned short*)p; p += (size_t)NNODES * 256 * 2;
    float* S       = (float*)p; p += (size_t)NNODES * 32 * 4;
    float* G       = (float*)p; p += (size_t)NNODES * 32 * 4;
    unsigned short* Wtf = (unsigned short*)p; p += 416 * 256 * 2;
    float* biascat = (float*)p; p += 416 * 4;
    unsigned short* y0f = (unsigned short*)p; p += (size_t)NPAD * 256 * 2;
    unsigned* einfo = (unsigned*)p; p += (size_t)NNODES * CAP * 4;
    int* cnt       = (int*)p;   p += NNODES * 4;

    // 1) fused prep: pack_a + prep_w + cnt-zero
    prep_pack<<<PACKA_BLOCKS + PREPW_BLOCKS + CNT_BLOCKS, 256, 0, stream>>>(
        Wq, bq, Wk, bk, Wv, bv, Wskip, bskip, x, t, Wtf, biascat, y0f, cnt);

    // 2) fused gemm + scatter (4B einfo entries, nontemporal stores)
    gemm_scatter<<<GEMM_BLOCKS, 256, 0, stream>>>(
        y0f, Wtf, biascat, Qb, KVb, S, ei, ew, cnt, einfo);

    // 3) edge aggregation
    agg_pass<<<(NNODES + 3) / 4, 256, 0, stream>>>(cnt, einfo, We, be, Qb, KVb, G);

    // 4) node MLP + film
    node_pass<<<(NNODES + 63) / 64, 256, 0, stream>>>(x, G, S, Wmlp, bmlp,
                                                      (float*)d_out);
}

// Round 10
// 246.428 us; speedup vs baseline: 1.1233x; 1.1233x over previous
//
#include <hip/hip_runtime.h>
#include <hip/hip_bf16.h>

#define NNODES 50000
#define NPAD   50048                 // 3128 row-tiles of 16 (covers 391*128)
#define NEDGES 800000
#define CAP 64                       // padded-CSR capacity (max degree ~45, Poisson(16))
#define RSQRT_D 0.17677669529663687f // 1/sqrt(32)
#define INV65535 1.5259021896696422e-05f

#define GEMM_BLOCKS 1564             // 391 stripes x 4 ct-groups
#define EHALF 400384                 // GEMM_BLOCKS*256 (edge e and e+EHALF per thread)

#define PREPW_BLOCKS 416
#define CNT_BLOCKS   196             // ceil(NNODES/256)

typedef short short8 __attribute__((ext_vector_type(8)));   // 8 bf16 (4 VGPRs)
typedef float f32x4 __attribute__((ext_vector_type(4)));    // MFMA accumulator

__device__ inline unsigned short f2bf(float f) {
    union { float f; unsigned u; } v; v.f = f;
    unsigned r = (v.u + 0x7fff + ((v.u >> 16) & 1)) >> 16;   // round-to-nearest-even
    return (unsigned short)r;
}
__device__ inline float bf2f(unsigned short u) {
    union { unsigned u; float f; } v; v.u = ((unsigned)u) << 16;
    return v.f;
}
// packed-bf16 dword -> two floats: 1 VALU op each (lshl / and)
__device__ inline float bflo(unsigned u) {
    union { unsigned u; float f; } v; v.u = u << 16; return v.f;
}
__device__ inline float bfhi(unsigned u) {
    union { unsigned u; float f; } v; v.u = u & 0xffff0000u; return v.f;
}
// branch-free tanh: 1 - 2/(e^{2x}+1). ~1e-6 abs err, saturates correctly.
__device__ inline float fast_tanh(float v) {
    const float e = __expf(2.0f * v);
    return 1.0f - 2.0f * __builtin_amdgcn_rcpf(e + 1.0f);
}

// ---------------------------------------------------------------------------
// prep: prep_w + cnt-zero. pack_a is GONE (round-10): the gemm reads x/t
// directly and converts to bf16 in-register — y0f (25.6MB write + 100MB
// re-read) was pure overhead since x is L3-resident either way (round-4
// lesson: that traffic is absorbed, not time).
// ---------------------------------------------------------------------------
__global__ __launch_bounds__(256) void prep(
    const float* __restrict__ Wq, const float* __restrict__ bq,
    const float* __restrict__ Wk, const float* __restrict__ bk,
    const float* __restrict__ Wv, const float* __restrict__ bv,
    const float* __restrict__ Wskip, const float* __restrict__ bskip,
    unsigned short* __restrict__ Wtf, float* __restrict__ biascat,
    int* __restrict__ cnt)
{
    const int b = blockIdx.x;
    const int tid = threadIdx.x;

    if (b < PREPW_BLOCKS) {
        // ---- prep_w: Wtf frag-major; chunk (ct*32+kt*4+quad) = 16 cols x 8 k ----
        const int col = b;
        const int k = tid;
        float v; float bb;
        if (col < 128)      { v = Wq[k * 128 + col];          bb = bq[col]; }
        else if (col < 256) { v = Wk[k * 128 + col - 128];    bb = bk[col - 128]; }
        else if (col < 384) { v = Wv[k * 128 + col - 256];    bb = bv[col - 256]; }
        else                { v = Wskip[k * 32 + col - 384];  bb = bskip[col - 384]; }
        const int ct = col >> 4, c16 = col & 15;
        const int kt = k >> 5, quad = (k >> 3) & 3, j = k & 7;
        Wtf[(size_t)(ct * 32 + kt * 4 + quad) * 128 + c16 * 8 + j] = f2bf(v);
        if (k == 0) biascat[col] = bb;
        return;
    }
    // ---- cnt zero ----
    const int idx = (b - PREPW_BLOCKS) * 256 + tid;
    if (idx < NNODES) cnt[idx] = 0;
}

// ---------------------------------------------------------------------------
// gemm_scatter v6 = round-8 v4 (known best: regular stores, 4B einfo)
// + DIRECT x/t load: B-frags built in-register from x (f2bf, t-mul, zero-
// mask for pad rows 50000..50047) — replaces the pack_a kernel entirely.
// Frag mapping preserved: b0[kt] holds row n0+l16, k = 32*kt + 8*quad
// (+128 => x * t half). Rounding identical to pack_a: f2bf(x), f2bf(x*t).
// Scatter: 2 edges/thread woven in; ei/ew + x loads issue before atomics;
// einfo stores after first DOTILE so the atomic round-trip hides under MFMA.
// ---------------------------------------------------------------------------
#define LOADW(buf, ct) do {                                                    \
    _Pragma("unroll")                                                          \
    for (int kt_ = 0; kt_ < 8; ++kt_)                                          \
        buf[kt_] = *(const short8*)(Wtf + (size_t)((ct) * 32 + kt_ * 4 + quad) * 128 + l16 * 8); \
} while (0)

#define DOTILE(buf, ct) do {                                                   \
    f32x4 acc0 = {0.f, 0.f, 0.f, 0.f}, acc1 = {0.f, 0.f, 0.f, 0.f};            \
    _Pragma("unroll")                                                          \
    for (int kt_ = 0; kt_ < 8; ++kt_) {                                        \
        acc0 = __builtin_amdgcn_mfma_f32_16x16x32_bf16(buf[kt_], b0[kt_], acc0, 0, 0, 0); \
        acc1 = __builtin_amdgcn_mfma_f32_16x16x32_bf16(buf[kt_], b1[kt_], acc1, 0, 0, 0); \
    }                                                                          \
    const int cb_ = (ct) * 16 + quad * 4;                                      \
    const float4 bias_ = *(const float4*)(biascat + cb_);                      \
    _Pragma("unroll")                                                          \
    for (int s_ = 0; s_ < 2; ++s_) {                                           \
        const int m_ = n0 + s_ * 16 + l16;                                     \
        if (m_ < NNODES) {                                                     \
            const f32x4 a_ = s_ ? acc1 : acc0;                                 \
            const float v0_ = a_[0] + bias_.x, v1_ = a_[1] + bias_.y;          \
            const float v2_ = a_[2] + bias_.z, v3_ = a_[3] + bias_.w;          \
            if ((ct) < 24) {                                                   \
                uint2 pk_;                                                     \
                pk_.x = (unsigned)f2bf(v0_) | ((unsigned)f2bf(v1_) << 16);     \
                pk_.y = (unsigned)f2bf(v2_) | ((unsigned)f2bf(v3_) << 16);     \
                if ((ct) < 8)                                                  \
                    *(uint2*)(Qb + (size_t)m_ * 128 + cb_) = pk_;              \
                else                                                           \
                    *(uint2*)(KVb + (size_t)m_ * 256 + (cb_ - 128)) = pk_;     \
            } else {                                                           \
                *(float4*)(S + (size_t)m_ * 32 + (cb_ - 384)) =                \
                    make_float4(v0_, v1_, v2_, v3_);                           \
            }                                                                  \
        }                                                                      \
    }                                                                          \
} while (0)

__global__ __launch_bounds__(256) void gemm_scatter(
    const float* __restrict__ x, const float* __restrict__ t,
    const unsigned short* __restrict__ Wtf,
    const float* __restrict__ biascat,
    unsigned short* __restrict__ Qb, unsigned short* __restrict__ KVb,
    float* __restrict__ S,
    const int* __restrict__ ei, const float* __restrict__ ew,
    int* __restrict__ cnt, unsigned* __restrict__ einfo)
{
    const int g = blockIdx.x;                          // 0..1563
    const int tid = threadIdx.x;

    // ---- scatter prologue: issue coalesced edge loads first ----
    const int gid = g * 256 + tid;                     // 0..400383
    const int e0 = gid;
    const int e1 = gid + EHALF;
    const bool m1 = e1 < NEDGES;                       // block-uniform (g>=1561 false)
    const int  s0 = ei[e0];
    const int  d0 = ei[NEDGES + e0];
    const float w0 = ew[e0];
    int s1 = 0, d1 = 0; float w1 = 0.f;
    if (m1) { s1 = ei[e1]; d1 = ei[NEDGES + e1]; w1 = ew[e1]; }

    // ---- gemm setup ----
    const int bx = g % 391;
    const int by = g / 391;                            // 0..3
    const int wave = tid >> 6;
    const int lane = tid & 63;
    const int l16 = lane & 15;
    const int quad = lane >> 4;

    const int n0 = bx * 128 + wave * 32;               // 32 rows per wave
    const int ct0 = by * 7 - ((by >= 2) ? (by - 2) : 0);   // 0,7,14,20
    const int nct = (by < 2) ? 7 : 6;
    const int ctEnd = ct0 + nct;

    // ---- build y0 B-frags DIRECTLY from x/t (replaces pack_a) ----
    // lane (l16, quad): b0 row = n0+l16, b1 row = n0+16+l16;
    // b{0,1}[kt], kt<4: x[row][32kt+8quad .. +8); kt>=4: same * t[row].
    const int row0 = n0 + l16;
    const int row1 = n0 + 16 + l16;
    const bool v0r = row0 < NNODES;
    const bool v1r = row1 < NNODES;
    const float msk0 = v0r ? 1.f : 0.f;
    const float msk1 = v1r ? 1.f : 0.f;
    const float* xr0 = x + (size_t)(v0r ? row0 : 0) * 128 + quad * 8;
    const float* xr1 = x + (size_t)(v1r ? row1 : 0) * 128 + quad * 8;
    const float tm0 = (v0r ? t[row0] : 0.f) * msk0;
    const float tm1 = (v1r ? t[row1] : 0.f) * msk1;

    // ---- fire atomics (round trip hides under conversion + first tiles) ----
    const int pos0 = atomicAdd(&cnt[d0], 1);
    const int pos1 = m1 ? atomicAdd(&cnt[d1], 1) : CAP;

    short8 b0[8], b1[8];
    #pragma unroll
    for (int k4 = 0; k4 < 4; ++k4) {
        const float4 a0 = *(const float4*)(xr0 + k4 * 32);
        const float4 a1 = *(const float4*)(xr0 + k4 * 32 + 4);
        const float4 c0 = *(const float4*)(xr1 + k4 * 32);
        const float4 c1 = *(const float4*)(xr1 + k4 * 32 + 4);
        short8 p;
        p[0] = (short)f2bf(a0.x * msk0); p[1] = (short)f2bf(a0.y * msk0);
        p[2] = (short)f2bf(a0.z * msk0); p[3] = (short)f2bf(a0.w * msk0);
        p[4] = (short)f2bf(a1.x * msk0); p[5] = (short)f2bf(a1.y * msk0);
        p[6] = (short)f2bf(a1.z * msk0); p[7] = (short)f2bf(a1.w * msk0);
        b0[k4] = p;
        p[0] = (short)f2bf(a0.x * tm0); p[1] = (short)f2bf(a0.y * tm0);
        p[2] = (short)f2bf(a0.z * tm0); p[3] = (short)f2bf(a0.w * tm0);
        p[4] = (short)f2bf(a1.x * tm0); p[5] = (short)f2bf(a1.y * tm0);
        p[6] = (short)f2bf(a1.z * tm0); p[7] = (short)f2bf(a1.w * tm0);
        b0[k4 + 4] = p;
        p[0] = (short)f2bf(c0.x * msk1); p[1] = (short)f2bf(c0.y * msk1);
        p[2] = (short)f2bf(c0.z * msk1); p[3] = (short)f2bf(c0.w * msk1);
        p[4] = (short)f2bf(c1.x * msk1); p[5] = (short)f2bf(c1.y * msk1);
        p[6] = (short)f2bf(c1.z * msk1); p[7] = (short)f2bf(c1.w * msk1);
        b1[k4] = p;
        p[0] = (short)f2bf(c0.x * tm1); p[1] = (short)f2bf(c0.y * tm1);
        p[2] = (short)f2bf(c0.z * tm1); p[3] = (short)f2bf(c0.w * tm1);
        p[4] = (short)f2bf(c1.x * tm1); p[5] = (short)f2bf(c1.y * tm1);
        p[6] = (short)f2bf(c1.z * tm1); p[7] = (short)f2bf(c1.w * tm1);
        b1[k4 + 4] = p;
    }

    short8 wa[8], wb[8];                               // ping-pong Wt A-frags
    LOADW(wa, ct0);
    LOADW(wb, ct0 + 1);
    DOTILE(wa, ct0);

    // ---- scatter epilogue: 4B packed entries ----
    if (pos0 < CAP) {
        const unsigned wq = (unsigned)(w0 * 65535.f + 0.5f);
        einfo[(size_t)d0 * CAP + pos0] = ((unsigned)s0 << 16) | wq;
    }
    if (pos1 < CAP) {
        const unsigned wq = (unsigned)(w1 * 65535.f + 0.5f);
        einfo[(size_t)d1 * CAP + pos1] = ((unsigned)s1 << 16) | wq;
    }

    for (int ct = ct0 + 1; ct < ctEnd; ct += 2) {
        if (ct + 1 < ctEnd) LOADW(wa, ct + 1);
        DOTILE(wb, ct);
        if (ct + 1 < ctEnd) {
            if (ct + 2 < ctEnd) LOADW(wb, ct + 2);
            DOTILE(wa, ct + 1);
        }
    }
}

// ---------------------------------------------------------------------------
// agg_pass (round-8 known-good: v2 structure + 4B einfo, regular loads):
// one wave per node; 16 lanes per edge (4 edges/batch), 16B per lane;
// 1-batch-ahead pipeline. CSR row preload = one 256B coalesced load; edge
// broadcast = one shfl. Decode: src = e>>16 (<<9 = *512B), w=(e&0xffff)/65535.
// Rank-1 edge-attr decomposition: p*(v+e) = p*v + (p*w)*We + p*be.
// At the L3 random-gather roofline (183MB @ ~3.4 TB/s) — structural floor.
// ---------------------------------------------------------------------------
__global__ __launch_bounds__(256) void agg_pass(
    const int* __restrict__ cnt, const unsigned* __restrict__ einfo,
    const float* __restrict__ We, const float* __restrict__ be,
    const unsigned short* __restrict__ Qb, const unsigned short* __restrict__ KVb,
    float* __restrict__ G)
{
    const int tid = threadIdx.x;
    const int node = blockIdx.x * 4 + (tid >> 6);
    if (node >= NNODES) return;
    const int l = tid & 63;
    const int slot = l >> 4;      // which edge of the 4-batch
    const int q = l & 15;         // 16 lanes/edge; lane covers dims q*8..q*8+7

    // Q fragment: 8 bf16 -> 8 f32
    const uint4 qu = *(const uint4*)(Qb + (size_t)node * 128 + q * 8);
    float qv[8];
    qv[0] = bflo(qu.x); qv[1] = bfhi(qu.x);
    qv[2] = bflo(qu.y); qv[3] = bfhi(qu.y);
    qv[4] = bflo(qu.z); qv[5] = bfhi(qu.z);
    qv[6] = bflo(qu.w); qv[7] = bfhi(qu.w);

    // We/be fragments for this lane's 8 dims (tiny, L2-hot)
    const float4 weA = *(const float4*)(We + q * 8);
    const float4 weB = *(const float4*)(We + q * 8 + 4);
    const float4 beA = *(const float4*)(be + q * 8);
    const float4 beB = *(const float4*)(be + q * 8 + 4);

    // per-head q.We / q.be scalars: partial over 8 dims, reduce over the
    // 4-lane head group (xor 1,2)
    float pw = qv[0]*weA.x + qv[1]*weA.y + qv[2]*weA.z + qv[3]*weA.w
             + qv[4]*weB.x + qv[5]*weB.y + qv[6]*weB.z + qv[7]*weB.w;
    float pb = qv[0]*beA.x + qv[1]*beA.y + qv[2]*beA.z + qv[3]*beA.w
             + qv[4]*beB.x + qv[5]*beB.y + qv[6]*beB.z + qv[7]*beB.w;
    pw += __shfl_xor(pw, 1); pb += __shfl_xor(pb, 1);
    pw += __shfl_xor(pw, 2); pb += __shfl_xor(pb, 2);
    const float qWeS = pw * RSQRT_D;
    const float qbeS = pb * RSQRT_D;

    const int deg = min(cnt[node], CAP);
    const unsigned* ep = einfo + (size_t)node * CAP;

    // whole CSR row in wave registers (one 256B coalesced load); zeros
    // elsewhere so shuffled-in garbage is a safe node-0 index / weight-0
    unsigned eall = 0;
    const int loadN = min(CAP, ((deg + 3) & ~3) + 4);
    if (l < loadN) eall = ep[l];

    float a[8] = {0.f, 0.f, 0.f, 0.f, 0.f, 0.f, 0.f, 0.f};
    float sp = 0.f, spw = 0.f;

    const char* kvb = (const char*)KVb;          // KV row = 512B (K:0..255, V:256..511)
    const unsigned qoff = (unsigned)(q * 16);

    // prologue: fetch batch 0
    unsigned ec = (unsigned)__shfl((int)eall, slot);
    bool vc = (slot < deg);
    {
        const unsigned off = (vc ? ((ec & 0xffff0000u) >> 7) : 0u) + qoff;
        uint4 kw = *(const uint4*)(kvb + off);
        uint4 vw = *(const uint4*)(kvb + off + 256);
        float wc = (float)(ec & 0xffffu) * INV65535;

        for (int jj = 0; jj < deg; jj += 4) {
            // --- prefetch next batch (issued before current compute) ---
            const int nidx = (jj + 4 + slot) & 63;
            const unsigned en = (unsigned)__shfl((int)eall, nidx);
            const bool vn = (jj + 4 + slot < deg);
            const unsigned offn = (vn ? ((en & 0xffff0000u) >> 7) : 0u) + qoff;
            const uint4 kwn = *(const uint4*)(kvb + offn);
            const uint4 vwn = *(const uint4*)(kvb + offn + 256);
            const float wn = (float)(en & 0xffffu) * INV65535;

            // --- compute current batch ---
            float d = qv[0]*bflo(kw.x) + qv[1]*bfhi(kw.x)
                    + qv[2]*bflo(kw.y) + qv[3]*bfhi(kw.y)
                    + qv[4]*bflo(kw.z) + qv[5]*bfhi(kw.z)
                    + qv[6]*bflo(kw.w) + qv[7]*bfhi(kw.w);
            d += __shfl_xor(d, 1);
            d += __shfl_xor(d, 2);               // full per-head dot on all 4 lanes
            float p = __expf(d * RSQRT_D + wc * qWeS + qbeS);
            p = vc ? p : 0.f;
            sp += p; spw += p * wc;
            a[0] += p * bflo(vw.x); a[1] += p * bfhi(vw.x);
            a[2] += p * bflo(vw.y); a[3] += p * bfhi(vw.y);
            a[4] += p * bflo(vw.z); a[5] += p * bfhi(vw.z);
            a[6] += p * bflo(vw.w); a[7] += p * bfhi(vw.w);

            kw = kwn; vw = vwn; wc = wn; vc = vn;
        }
    }

    // reduce over the 4 edge slots (lane bits 4,5)
    sp  += __shfl_xor(sp, 16);  sp  += __shfl_xor(sp, 32);
    spw += __shfl_xor(spw, 16); spw += __shfl_xor(spw, 32);
    #pragma unroll
    for (int i = 0; i < 8; ++i) {
        a[i] += __shfl_xor(a[i], 16);
        a[i] += __shfl_xor(a[i], 32);
    }

    // per-head normalize + rank-1 edge-attr contribution
    const float inv = 1.f / (sp + 1e-16f);
    a[0] = (a[0] + spw*weA.x + sp*beA.x) * inv;
    a[1] = (a[1] + spw*weA.y + sp*beA.y) * inv;
    a[2] = (a[2] + spw*weA.z + sp*beA.z) * inv;
    a[3] = (a[3] + spw*weA.w + sp*beA.w) * inv;
    a[4] = (a[4] + spw*weB.x + sp*beB.x) * inv;
    a[5] = (a[5] + spw*weB.y + sp*beB.y) * inv;
    a[6] = (a[6] + spw*weB.z + sp*beB.z) * inv;
    a[7] = (a[7] + spw*weB.w + sp*beB.w) * inv;

    // mean over the 4 heads (lane bits 2,3)
    #pragma unroll
    for (int i = 0; i < 8; ++i) {
        a[i] += __shfl_xor(a[i], 4);
        a[i] += __shfl_xor(a[i], 8);
    }

    if (l < 4) {   // slot 0, q = 0..3 -> dims q*8..q*8+7
        *(float4*)(G + (size_t)node * 32 + q * 8) =
            make_float4(a[0]*0.25f, a[1]*0.25f, a[2]*0.25f, a[3]*0.25f);
        *(float4*)(G + (size_t)node * 32 + q * 8 + 4) =
            make_float4(a[4]*0.25f, a[5]*0.25f, a[6]*0.25f, a[7]*0.25f);
    }
}

// ---------------------------------------------------------------------------
// node_pass (v2): Wm lives in VGPRs, not LDS. Each thread's column pair
// (c, c+128) with c = tid&127 is invariant across the node loop; the 64
// weights fit in 64 VGPRs, loaded ONCE from global (coalesced, L2-hot).
// LDS keeps only yl (8 KB). Inner loop per node: 8 broadcast ds_read_b128
// + 64 reg-reg FMAs + 2 fast_tanh.
// ---------------------------------------------------------------------------
__global__ __launch_bounds__(256, 4) void node_pass(
    const float* __restrict__ x,
    const float* __restrict__ G, const float* __restrict__ S,
    const float* __restrict__ Wmlp, const float* __restrict__ bmlp,
    float* __restrict__ out)
{
    __shared__ float yl[64 * 32];

    const int tid = threadIdx.x;
    const int c = tid & 127;            // fixed output column pair (c, c+128)
    const int half = tid >> 7;          // which node of each row pair

    float w1[32], w2[32];
    #pragma unroll
    for (int d = 0; d < 32; ++d) {
        w1[d] = Wmlp[d * 256 + c];
        w2[d] = Wmlp[d * 256 + c + 128];
    }
    const float b1 = bmlp[c];
    const float b2 = bmlp[c + 128];

    const int n0 = blockIdx.x * 64;

    // stage y = tanh(G+S): 512 float4s by 256 threads, vectorized
    for (int i4 = tid; i4 < 512; i4 += 256) {
        const int n = n0 + (i4 >> 3);
        const int d0 = (i4 & 7) * 4;
        float4 yv = make_float4(0.f, 0.f, 0.f, 0.f);
        if (n < NNODES) {
            const float4 gv = *(const float4*)(G + (size_t)n * 32 + d0);
            const float4 sv = *(const float4*)(S + (size_t)n * 32 + d0);
            yv.x = fast_tanh(gv.x + sv.x);
            yv.y = fast_tanh(gv.y + sv.y);
            yv.z = fast_tanh(gv.z + sv.z);
            yv.w = fast_tanh(gv.w + sv.w);
        }
        *(float4*)&yl[i4 * 4] = yv;
    }
    __syncthreads();

    for (int k = 0; k < 32; ++k) {
        const int nl = 2 * k + half;
        const int n = n0 + nl;
        if (n >= NNODES) continue;

        const float4* yr = (const float4*)&yl[nl * 32];  // wave-uniform -> broadcast
        float s1 = b1, s2 = b2;
        #pragma unroll
        for (int d8 = 0; d8 < 8; ++d8) {
            const float4 y4 = yr[d8];
            s1 = fmaf(y4.x, w1[d8 * 4 + 0], s1);
            s2 = fmaf(y4.x, w2[d8 * 4 + 0], s2);
            s1 = fmaf(y4.y, w1[d8 * 4 + 1], s1);
            s2 = fmaf(y4.y, w2[d8 * 4 + 1], s2);
            s1 = fmaf(y4.z, w1[d8 * 4 + 2], s1);
            s2 = fmaf(y4.z, w2[d8 * 4 + 2], s2);
            s1 = fmaf(y4.w, w1[d8 * 4 + 3], s1);
            s2 = fmaf(y4.w, w2[d8 * 4 + 3], s2);
        }
        const float z1 = fast_tanh(s1);
        const float z2 = fast_tanh(s2);
        out[(size_t)n * 128 + c] = fmaf(x[(size_t)n * 128 + c], z1, z2);
    }
}

// ---------------------------------------------------------------------------
extern "C" void kernel_launch(void* const* d_in, const int* in_sizes, int n_in,
                              void* d_out, int out_size, void* d_ws, size_t ws_size,
                              hipStream_t stream) {
    const float* x     = (const float*)d_in[0];
    const float* t     = (const float*)d_in[1];
    const int*   ei    = (const int*)  d_in[2];
    const float* ew    = (const float*)d_in[3];
    const float* Wq    = (const float*)d_in[4];
    const float* bq    = (const float*)d_in[5];
    const float* Wk    = (const float*)d_in[6];
    const float* bk    = (const float*)d_in[7];
    const float* Wv    = (const float*)d_in[8];
    const float* bv    = (const float*)d_in[9];
    const float* We    = (const float*)d_in[10];
    const float* be    = (const float*)d_in[11];
    const float* Wskip = (const float*)d_in[12];
    const float* bskip = (const float*)d_in[13];
    const float* Wmlp  = (const float*)d_in[14];
    const float* bmlp  = (const float*)d_in[15];

    char* p = (char*)d_ws;
    unsigned short* Qb  = (unsigned short*)p; p += (size_t)NNODES * 128 * 2;
    unsigned short* KVb = (unsigned short*)p; p += (size_t)NNODES * 256 * 2;
    float* S       = (float*)p; p += (size_t)NNODES * 32 * 4;
    float* G       = (float*)p; p += (size_t)NNODES * 32 * 4;
    unsigned short* Wtf = (unsigned short*)p; p += 416 * 256 * 2;
    float* biascat = (float*)p; p += 416 * 4;
    unsigned* einfo = (unsigned*)p; p += (size_t)NNODES * CAP * 4;
    int* cnt       = (int*)p;   p += NNODES * 4;

    // 1) prep: Wtf/biascat + cnt-zero (pack_a eliminated)
    prep<<<PREPW_BLOCKS + CNT_BLOCKS, 256, 0, stream>>>(
        Wq, bq, Wk, bk, Wv, bv, Wskip, bskip, Wtf, biascat, cnt);

    // 2) fused gemm + scatter (direct x/t read, in-register bf16 convert)
    gemm_scatter<<<GEMM_BLOCKS, 256, 0, stream>>>(
        x, t, Wtf, biascat, Qb, KVb, S, ei, ew, cnt, einfo);

    // 3) edge aggregation
    agg_pass<<<(NNODES + 3) / 4, 256, 0, stream>>>(cnt, einfo, We, be, Qb, KVb, G);

    // 4) node MLP + film
    node_pass<<<(NNODES + 63) / 64, 256, 0, stream>>>(x, G, S, Wmlp, bmlp,
                                                      (float*)d_out);
}